// Round 10
// baseline (369.482 us; speedup 1.0000x reference)
//
#include <hip/hip_runtime.h>
#include <stdint.h>

typedef unsigned int u32;
typedef unsigned short u16;
typedef __attribute__((ext_vector_type(8))) short bf16x8;
typedef __attribute__((ext_vector_type(4))) float f32x4;

#define BUF_ELEMS (16384 * 256)

__device__ __forceinline__ float bflo(u32 u) { return __uint_as_float(u << 16); }
__device__ __forceinline__ float bfhi(u32 u) { return __uint_as_float(u & 0xffff0000u); }
__device__ __forceinline__ u16 f2bf(float f) {
    u32 u = __float_as_uint(f);
    return (u16)((u + 0x7fffu + ((u >> 16) & 1u)) >> 16);
}
// pack high halves of two f32 -> u32 (truncation-round bf16 pair, lo first)
__device__ __forceinline__ u32 pkhi(float lo, float hi) {
    return __builtin_amdgcn_perm(__float_as_uint(hi), __float_as_uint(lo), 0x07060302u);
}

// ---------------------------------------------------------------------------
// wtrans: 9x W[k][n] fp32 -> Wt[n][k] bf16; block 160 = QKV bias concat.
// ---------------------------------------------------------------------------
struct WT {
    const float* src[9];
    u16* dst[9];
    const float* bs[6];   // bq_i, bk_t, bv_t, bq_t, bk_i, bv_i
    float* bA;            // [768]
    float* bB;            // [768]
};

__global__ __launch_bounds__(256)
void wtrans_kernel(WT wt)
{
    __shared__ float T[64][65];
    const int bid = blockIdx.x, t = threadIdx.x;
    if (bid == 160) {
        wt.bA[t]       = wt.bs[0][t];
        wt.bA[256 + t] = wt.bs[1][t];
        wt.bA[512 + t] = wt.bs[2][t];
        wt.bB[t]       = wt.bs[3][t];
        wt.bB[256 + t] = wt.bs[4][t];
        wt.bB[512 + t] = wt.bs[5][t];
        return;
    }
    int m, sub;
    if (bid < 128) { m = bid >> 4; sub = bid & 15; }
    else           { m = 8;        sub = bid - 128; }
    const int K = (m == 8) ? 512 : 256;
    const int kt = (m == 8) ? (sub & 7) : (sub & 3);
    const int nt = (m == 8) ? (sub >> 3) : (sub >> 2);
    const int k0 = kt * 64, n0 = nt * 64;
    const float* src = wt.src[m];
    u16* dst = wt.dst[m];

    const int kk = t >> 2, nn = (t & 3) * 16;
    #pragma unroll
    for (int j = 0; j < 16; j += 4) {
        float4 v = *(const float4*)(src + (size_t)(k0 + kk) * 256 + n0 + nn + j);
        T[kk][nn + j + 0] = v.x; T[kk][nn + j + 1] = v.y;
        T[kk][nn + j + 2] = v.z; T[kk][nn + j + 3] = v.w;
    }
    __syncthreads();
    const int nn2 = t >> 2, kc = (t & 3) * 16;
    #pragma unroll
    for (int j = 0; j < 16; j++)
        dst[(size_t)(n0 + nn2) * K + k0 + kc + j] = f2bf(T[kc + j][nn2]);
}

// ---------------------------------------------------------------------------
// Unified MFMA GEMM. 128x128 tile, 4 waves (2x2 of 64x64), BK=64.
// Supergroup swizzle: the n-tiles sharing one A row-block sit 8 bids apart
// (same XCD) inside one contiguous supergroup (temporally co-resident).
// MODE 0 QKV : A fp32 img/txt m-stacked (in-register cvt), N=768, K=256.
//              Q n-group (n_idx<2) pre-scaled by 1/sqrt(32)*log2(e).
//              grid 1536; bid = (m>>3)*48 + n*8 + (m&7).
// MODE 1 OPRJ: A bf16, M=32768 m-stacked, N=256. grid 512;
//              bid = (m>>3)*16 + n*8 + (m&7).
// MODE 2 ENH : A bf16 x2 kt-concat (K=512), N=256, fp32 out. grid 272:
//              bids 0..255 gemm (same swizzle as MODE 1 with 128 m-blocks),
//              bids 256..271 = inconsistency GEMM + passthroughs.
// ---------------------------------------------------------------------------
template<int MODE>
__global__ __launch_bounds__(256)
void gemm_mfma(const float* __restrict__ Af0, const float* __restrict__ Af1,
               const u16* __restrict__ Ab0, const u16* __restrict__ Ab1,
               const u16* __restrict__ Wt0, const u16* __restrict__ Wt1,
               const float* __restrict__ bias0, const float* __restrict__ bias1,
               void* __restrict__ o0, void* __restrict__ o1, void* __restrict__ o2,
               void* __restrict__ o3, void* __restrict__ o4, void* __restrict__ o5)
{
    __shared__ u16 As[128][72];
    __shared__ u16 Bs[128][72];
    const int tid = threadIdx.x;

    // ---- MODE 2 tail blocks: inconsistency GEMM + passthroughs ----
    if (MODE == 2 && blockIdx.x >= 256) {
        float* iv = (float*)&As[0][0];   // 512 floats of the As area
        const int b = blockIdx.x - 256, n = tid;
        float a = Af0[b * 256 + n];      // img_specific
        float x = Af1[b * 256 + n];      // txt_specific
        iv[n] = a - x;
        iv[256 + n] = a * x;
        __syncthreads();
        const float* Wi = (const float*)Wt1;   // incw [512,256]
        float a0 = bias1[n], a1 = 0.f, a2 = 0.f, a3 = 0.f;
        #pragma unroll 2
        for (int k = 0; k < 512; k += 4) {
            a0 += iv[k]     * Wi[(k)     * 256 + n];
            a1 += iv[k + 1] * Wi[(k + 1) * 256 + n];
            a2 += iv[k + 2] * Wi[(k + 2) * 256 + n];
            a3 += iv[k + 3] * Wi[(k + 3) * 256 + n];
        }
        ((float*)o1)[b * 256 + n] = (a0 + a1) + (a2 + a3);
        ((float*)o2)[b * 256 + n] = a;
        ((float*)o3)[b * 256 + n] = x;
        return;
    }

    const int wave = tid >> 6, lane = tid & 63;
    const int L = lane & 15, Qd = lane >> 4;
    int m_idx, n_idx;
    if (MODE == 0) {
        const int sup = blockIdx.x / 48, rem = blockIdx.x % 48;
        n_idx = rem >> 3; m_idx = sup * 8 + (rem & 7);
    } else {
        const int sup = blockIdx.x >> 4, rem = blockIdx.x & 15;
        n_idx = (rem >> 3) & 1; m_idx = sup * 8 + (rem & 7);
    }
    const bool ms = (MODE != 2) && (m_idx >= 128);
    const int lm0 = (MODE == 2) ? m_idx * 128 : (m_idx & 127) * 128;
    const int n0 = n_idx * 128;
    const u16* Wt = ms ? Wt1 : Wt0;
    const float* bias = ms ? bias1 : bias0;
    const int wr = wave & 1, wc = wave >> 1;
    const int sr = tid >> 1, sh = (tid & 1) * 32;
    const int KS = (MODE == 2) ? 512 : 256;

    f32x4 acc[4][4] = {};

    for (int kt = 0; kt < KS; kt += 64) {
        // ---- stage A ----
        if (MODE == 0) {
            const float* Af = ms ? Af1 : Af0;
            const float* Ap = Af + (size_t)(lm0 + sr) * 256 + kt + sh;
            uint4 pk[2];
            #pragma unroll
            for (int half = 0; half < 2; half++) {
                float4 f0 = *(const float4*)(Ap + half * 16);
                float4 f1 = *(const float4*)(Ap + half * 16 + 4);
                float4 f2 = *(const float4*)(Ap + half * 16 + 8);
                float4 f3 = *(const float4*)(Ap + half * 16 + 12);
                pk[half].x = pkhi(f0.x, f0.y);
                pk[half].y = pkhi(f0.z, f0.w);
                pk[half].z = pkhi(f1.x, f1.y);
                pk[half].w = pkhi(f1.z, f1.w);
                uint4 q;
                q.x = pkhi(f2.x, f2.y); q.y = pkhi(f2.z, f2.w);
                q.z = pkhi(f3.x, f3.y); q.w = pkhi(f3.z, f3.w);
                *(uint4*)&As[sr][sh + half * 16 + 8] = q;
            }
            *(uint4*)&As[sr][sh + 0] = pk[0];
            *(uint4*)&As[sr][sh + 16] = pk[1];
        } else {
            const u16* Abase;
            int lkt = kt;
            if (MODE == 2) { Abase = (kt < 256) ? Ab0 : Ab1; lkt = kt & 255; }
            else           { Abase = ms ? Ab1 : Ab0; }
            const u16* Ap = Abase + (size_t)(lm0 + sr) * 256 + lkt + sh;
            uint4 a0 = *(const uint4*)(Ap + 0);
            uint4 a1 = *(const uint4*)(Ap + 8);
            uint4 a2 = *(const uint4*)(Ap + 16);
            uint4 a3 = *(const uint4*)(Ap + 24);
            *(uint4*)&As[sr][sh + 0]  = a0;
            *(uint4*)&As[sr][sh + 8]  = a1;
            *(uint4*)&As[sr][sh + 16] = a2;
            *(uint4*)&As[sr][sh + 24] = a3;
        }
        // ---- stage B (Wt is n-major [n][k], stride KS) ----
        {
            const u16* Bp = Wt + (size_t)(n0 + sr) * KS + kt + sh;
            uint4 w0 = *(const uint4*)(Bp + 0);
            uint4 w1 = *(const uint4*)(Bp + 8);
            uint4 w2 = *(const uint4*)(Bp + 16);
            uint4 w3 = *(const uint4*)(Bp + 24);
            *(uint4*)&Bs[sr][sh + 0]  = w0;
            *(uint4*)&Bs[sr][sh + 8]  = w1;
            *(uint4*)&Bs[sr][sh + 16] = w2;
            *(uint4*)&Bs[sr][sh + 24] = w3;
        }
        __syncthreads();
        #pragma unroll
        for (int kh = 0; kh < 64; kh += 32) {
            bf16x8 af[4], bf[4];
            #pragma unroll
            for (int mt = 0; mt < 4; mt++)
                af[mt] = *(const bf16x8*)&As[wr * 64 + mt * 16 + L][kh + Qd * 8];
            #pragma unroll
            for (int nt = 0; nt < 4; nt++)
                bf[nt] = *(const bf16x8*)&Bs[wc * 64 + nt * 16 + L][kh + Qd * 8];
            #pragma unroll
            for (int mt = 0; mt < 4; mt++)
                #pragma unroll
                for (int nt = 0; nt < 4; nt++)
                    acc[mt][nt] = __builtin_amdgcn_mfma_f32_16x16x32_bf16(
                        af[mt], bf[nt], acc[mt][nt], 0, 0, 0);
        }
        __syncthreads();
    }

    // ---- epilogue ----
    float bvals[4];
    #pragma unroll
    for (int nt = 0; nt < 4; nt++)
        bvals[nt] = bias[n0 + wc * 64 + nt * 16 + L];

    const float qsc = (MODE == 0 && n_idx < 2)
                      ? (0.17677669529663687f * 1.4426950408889634f) : 1.0f;

    void* outp;
    int colb;
    if (MODE == 0) {
        const int g = n_idx >> 1;
        if (!ms) outp = (g == 0) ? o0 : ((g == 1) ? o1 : o2);
        else     outp = (g == 0) ? o3 : ((g == 1) ? o4 : o5);
        colb = (n_idx & 1) * 128 + wc * 64;
    } else if (MODE == 1) {
        outp = ms ? o1 : o0;
        colb = n0 + wc * 64;
    } else {
        outp = o0;
        colb = n0 + wc * 64;
    }
    #pragma unroll
    for (int mt = 0; mt < 4; mt++) {
        #pragma unroll
        for (int r = 0; r < 4; r++) {
            const size_t row = (size_t)(lm0 + wr * 64 + mt * 16 + Qd * 4 + r) * 256;
            #pragma unroll
            for (int nt = 0; nt < 4; nt++) {
                const int col = colb + nt * 16 + L;
                float v = (acc[mt][nt][r] + bvals[nt]) * qsc;
                if (MODE == 2) ((float*)outp)[row + col] = v;
                else           ((u16*)outp)[row + col] = f2bf(v);
            }
        }
    }
}

// ---------------------------------------------------------------------------
// MFMA flash attention. K fragments read DIRECT from global (L2-hot; no Ks
// LDS) -> LDS 26.1 KB -> 5 blocks/CU. Supergroup swizzle: the 8 qt-sharers
// of one (b,h) sit 8 bids apart inside one 64-bid supergroup (same XCD,
// co-resident). Virtual key order for b128 P-writes; ones-B MFMA row sums;
// Q pre-scaled -> bare exp2f. Output in-place over Q. grid 2048; block 256.
// ---------------------------------------------------------------------------
__global__ __launch_bounds__(256, 5)
void attn_mfma(const u16* __restrict__ Q0, const u16* __restrict__ K0,
               const u16* __restrict__ V0, u16* __restrict__ O0,
               const u16* __restrict__ Q1, const u16* __restrict__ K1,
               const u16* __restrict__ V1, u16* __restrict__ O1)
{
    __shared__ u16 Vt[32][136];      // [dim][v-key]
    __shared__ u16 Ps[4][16][136];   // [wave][q][v-key], reused across qs
    const int tid = threadIdx.x;
    const int wave = tid >> 6, lane = tid & 63;
    const int L = lane & 15, Qd = lane >> 4;
    const int bid = blockIdx.x;
    const int sup = bid >> 6, rem = bid & 63;
    const int qt = rem >> 3;
    const int kvl = sup * 8 + (rem & 7);  // 0..255
    const int set = kvl >> 7;
    const int b = (kvl >> 3) & 15;
    const int h = kvl & 7;
    const u16* Q = set ? Q1 : Q0;
    const u16* K = set ? K1 : K0;
    const u16* V = set ? V1 : V0;
    u16* O = set ? O1 : O0;
    const int rowbase = b * 1024;
    const int qbase = rowbase + qt * 128;

    bf16x8 qfrag[2];
    #pragma unroll
    for (int qs = 0; qs < 2; qs++)
        qfrag[qs] = *(const bf16x8*)(Q + (size_t)(qbase + qs * 64 + wave * 16 + L) * 256
                                       + h * 32 + Qd * 8);

    const short oneb = (short)0x3F80;
    const bf16x8 ones = {oneb, oneb, oneb, oneb, oneb, oneb, oneb, oneb};

    f32x4 oacc[2][2] = {};
    f32x4 oaccL[2] = {};

    const int sr = tid >> 1;          // key 0..127
    const int scol = (tid & 1) * 16;  // dim half
    const int vcol = (sr & 15) * 8 + (sr >> 4);

    for (int t = 0; t < 8; t++) {
        // ---- stage V^T only ----
        const size_t kvbase = (size_t)(rowbase + t * 128 + sr) * 256 + h * 32 + scol;
        uint4 v1 = *(const uint4*)(V + kvbase);
        uint4 v2 = *(const uint4*)(V + kvbase + 8);
        union { uint4 u4[2]; u16 us[16]; } vv;
        vv.u4[0] = v1; vv.u4[1] = v2;
        #pragma unroll
        for (int j = 0; j < 16; j++) Vt[scol + j][vcol] = vv.us[j];

        // ---- K fragments direct from global (wave-identical, L2-served) ----
        const u16* Kb = K + (size_t)(rowbase + t * 128 + L) * 256 + h * 32 + Qd * 8;
        bf16x8 kf[8];
        #pragma unroll
        for (int ct = 0; ct < 8; ct++)
            kf[ct] = *(const bf16x8*)(Kb + (size_t)ct * 16 * 256);

        __syncthreads();

        #pragma unroll
        for (int qs = 0; qs < 2; qs++) {
            const f32x4 z = {0.f, 0.f, 0.f, 0.f};
            f32x4 sacc[8];
            #pragma unroll
            for (int ct = 0; ct < 8; ct++)
                sacc[ct] = __builtin_amdgcn_mfma_f32_16x16x32_bf16(qfrag[qs], kf[ct], z, 0, 0, 0);
            #pragma unroll
            for (int r = 0; r < 4; r++) {
                float p[8];
                #pragma unroll
                for (int ct = 0; ct < 8; ct++) p[ct] = exp2f(sacc[ct][r]);
                uint4 pk;
                pk.x = pkhi(p[0], p[1]);
                pk.y = pkhi(p[2], p[3]);
                pk.z = pkhi(p[4], p[5]);
                pk.w = pkhi(p[6], p[7]);
                *(uint4*)&Ps[wave][Qd * 4 + r][L * 8] = pk;
            }
            #pragma unroll
            for (int kc = 0; kc < 4; kc++) {
                bf16x8 pfrag = *(const bf16x8*)&Ps[wave][L][kc * 32 + Qd * 8];
                bf16x8 vf0 = *(const bf16x8*)&Vt[L][kc * 32 + Qd * 8];
                bf16x8 vf1 = *(const bf16x8*)&Vt[16 + L][kc * 32 + Qd * 8];
                oacc[qs][0] = __builtin_amdgcn_mfma_f32_16x16x32_bf16(pfrag, vf0, oacc[qs][0], 0, 0, 0);
                oacc[qs][1] = __builtin_amdgcn_mfma_f32_16x16x32_bf16(pfrag, vf1, oacc[qs][1], 0, 0, 0);
                oaccL[qs]   = __builtin_amdgcn_mfma_f32_16x16x32_bf16(pfrag, ones, oaccL[qs], 0, 0, 0);
            }
        }
        __syncthreads();
    }

    #pragma unroll
    for (int qs = 0; qs < 2; qs++) {
        #pragma unroll
        for (int r = 0; r < 4; r++) {
            float inv = 1.f / oaccL[qs][r];
            const size_t orow = (size_t)(qbase + qs * 64 + wave * 16 + Qd * 4 + r) * 256 + h * 32;
            O[orow + L]      = f2bf(oacc[qs][0][r] * inv);
            O[orow + 16 + L] = f2bf(oacc[qs][1][r] * inv);
        }
    }
}

// ---------------------------------------------------------------------------
// Residual + LayerNorm, both halves in one dispatch.
// ---------------------------------------------------------------------------
__global__ __launch_bounds__(256)
void ln_res_kernel(const u16* __restrict__ P0, const u16* __restrict__ P1,
                   const float* __restrict__ R0, const float* __restrict__ R1,
                   const float* __restrict__ g0, const float* __restrict__ be0,
                   const float* __restrict__ g1, const float* __restrict__ be1,
                   u16* __restrict__ out0, u16* __restrict__ out1)
{
    const int lane = threadIdx.x & 63;
    int row = blockIdx.x * 4 + (threadIdx.x >> 6);
    const bool sel = row >= 16384;
    const u16* P = sel ? P1 : P0;
    const float* R = sel ? R1 : R0;
    const float* g = sel ? g1 : g0;
    const float* be = sel ? be1 : be0;
    u16* out = sel ? out1 : out0;
    if (sel) row -= 16384;
    const int col = lane * 4;
    uint2 pv = *(const uint2*)(P + (size_t)row * 256 + col);
    float4 rv = *(const float4*)(R + (size_t)row * 256 + col);
    float x0 = bflo(pv.x) + rv.x;
    float x1 = bfhi(pv.x) + rv.y;
    float x2 = bflo(pv.y) + rv.z;
    float x3 = bfhi(pv.y) + rv.w;
    float s = x0 + x1 + x2 + x3;
    float s2 = x0*x0 + x1*x1 + x2*x2 + x3*x3;
    #pragma unroll
    for (int off = 32; off > 0; off >>= 1) {
        s  += __shfl_xor(s, off);
        s2 += __shfl_xor(s2, off);
    }
    float mean = s * 0.00390625f;
    float var = fmaxf(s2 * 0.00390625f - mean * mean, 0.f);
    float rstd = rsqrtf(var + 1e-5f);
    float4 gv = *(const float4*)(g + col);
    float4 bv = *(const float4*)(be + col);
    uint2 pk;
    pk.x = (u32)f2bf((x0 - mean) * rstd * gv.x + bv.x)
         | ((u32)f2bf((x1 - mean) * rstd * gv.y + bv.y) << 16);
    pk.y = (u32)f2bf((x2 - mean) * rstd * gv.z + bv.z)
         | ((u32)f2bf((x3 - mean) * rstd * gv.w + bv.w) << 16);
    *(uint2*)(out + (size_t)row * 256 + col) = pk;
}

// ---------------------------------------------------------------------------
extern "C" void kernel_launch(void* const* d_in, const int* in_sizes, int n_in,
                              void* d_out, int out_size, void* d_ws, size_t ws_size,
                              hipStream_t stream)
{
    (void)in_sizes; (void)n_in; (void)out_size; (void)ws_size;
    const float* img    = (const float*)d_in[0];
    const float* txt    = (const float*)d_in[1];
    const float* img_sp = (const float*)d_in[2];
    const float* txt_sp = (const float*)d_in[3];
    const float* wq_i = (const float*)d_in[4];  const float* bq_i = (const float*)d_in[5];
    const float* wk_i = (const float*)d_in[6];  const float* bk_i = (const float*)d_in[7];
    const float* wv_i = (const float*)d_in[8];  const float* bv_i = (const float*)d_in[9];
    const float* wo_i = (const float*)d_in[10]; const float* bo_i = (const float*)d_in[11];
    const float* wq_t = (const float*)d_in[12]; const float* bq_t = (const float*)d_in[13];
    const float* wk_t = (const float*)d_in[14]; const float* bk_t = (const float*)d_in[15];
    const float* wv_t = (const float*)d_in[16]; const float* bv_t = (const float*)d_in[17];
    const float* wo_t = (const float*)d_in[18]; const float* bo_t = (const float*)d_in[19];
    const float* lng_i = (const float*)d_in[20]; const float* lnb_i = (const float*)d_in[21];
    const float* lng_t = (const float*)d_in[22]; const float* lnb_t = (const float*)d_in[23];
    const float* enh_w = (const float*)d_in[24]; const float* enh_b = (const float*)d_in[25];
    const float* incw  = (const float*)d_in[26]; const float* incb  = (const float*)d_in[27];
    float* out = (float*)d_out;
    u16* wsp = (u16*)d_ws;
    u16* B0 = wsp;
    u16* B1 = wsp + 1 * (size_t)BUF_ELEMS;
    u16* B2 = wsp + 2 * (size_t)BUF_ELEMS;
    u16* B3 = wsp + 3 * (size_t)BUF_ELEMS;
    u16* B4 = wsp + 4 * (size_t)BUF_ELEMS;
    u16* B5 = wsp + 5 * (size_t)BUF_ELEMS;
    u16* wbase = wsp + 6 * (size_t)BUF_ELEMS;
    u16* WtA   = wbase;                 // [768][256]: Wq_i^T, Wk_t^T, Wv_t^T
    u16* WtB   = wbase + 196608;        // [768][256]: Wq_t^T, Wk_i^T, Wv_i^T
    u16* Wt_oi = wbase + 393216;
    u16* Wt_ot = wbase + 458752;
    u16* Wt_en = wbase + 524288;        // [256][512]
    float* biasA = (float*)(wbase + 655360);  // [768]
    float* biasB = biasA + 768;

    dim3 blk(256);
    // ---- prep: weights + biases ----
    WT wt;
    wt.src[0] = wq_i; wt.dst[0] = WtA;
    wt.src[1] = wk_t; wt.dst[1] = WtA + 65536;
    wt.src[2] = wv_t; wt.dst[2] = WtA + 131072;
    wt.src[3] = wq_t; wt.dst[3] = WtB;
    wt.src[4] = wk_i; wt.dst[4] = WtB + 65536;
    wt.src[5] = wv_i; wt.dst[5] = WtB + 131072;
    wt.src[6] = wo_i; wt.dst[6] = Wt_oi;
    wt.src[7] = wo_t; wt.dst[7] = Wt_ot;
    wt.src[8] = enh_w; wt.dst[8] = Wt_en;
    wt.bs[0] = bq_i; wt.bs[1] = bk_t; wt.bs[2] = bv_t;
    wt.bs[3] = bq_t; wt.bs[4] = bk_i; wt.bs[5] = bv_i;
    wt.bA = biasA; wt.bB = biasB;
    wtrans_kernel<<<161, blk, 0, stream>>>(wt);

    // ---- merged QKV projections ----
    // img -> (Q_i2t=B0, K_t2i=B4, V_t2i=B5); txt -> (Q_t2i=B3, K_i2t=B1, V_i2t=B2)
    gemm_mfma<0><<<1536, blk, 0, stream>>>(img, txt, nullptr, nullptr,
                                           WtA, WtB, biasA, biasB,
                                           B0, B4, B5, B3, B1, B2);
    // ---- both attentions, output in-place over Q ----
    attn_mfma<<<2048, blk, 0, stream>>>(B0, B1, B2, B0, B3, B4, B5, B3);
    // ---- output projections, M-stacked ----
    gemm_mfma<1><<<512, blk, 0, stream>>>(nullptr, nullptr, B0, B3,
                                          Wt_oi, Wt_ot, bo_i, bo_t,
                                          B1, B4, nullptr, nullptr, nullptr, nullptr);
    // ---- residual + LN, both halves ----
    ln_res_kernel<<<8192, blk, 0, stream>>>(B1, B4, img, txt,
                                            lng_i, lnb_i, lng_t, lnb_t, B2, B5);
    // ---- enhancement (fp32 out) + inconsistency tail blocks ----
    gemm_mfma<2><<<272, blk, 0, stream>>>(img_sp, txt_sp, B2, B5,
                                          Wt_en, (const u16*)incw, enh_b, incb,
                                          out, out + 4194304, out + 4198400,
                                          out + 4202496, nullptr, nullptr);
}